// Round 1
// baseline (4116.819 us; speedup 1.0000x reference)
//
#include <hip/hip_runtime.h>
#include <hip/hip_bf16.h>
#include <math.h>

// Shapes: B=1, S=512, N=384, c_m=64, c_z=128, H=8, c=32  (HC = H*c = 256)
// Stage 1: m = LN(m_si); v = m@W1 (bf16 ws); g = sigmoid(m@W3) (bf16 ws)
// Stage 2: b = LN(z)@W2  -> w_buf[h][i][j] (fp32 ws)
// Stage 3: softmax over i (in place)
// Stage 4: o[s,i,h,c] = g * sum_j w[h,i,j]*v[s,j,h,c]; out = o @ W4

__global__ __launch_bounds__(256) void k1_ln_mv(
    const float* __restrict__ m_si,
    const float* __restrict__ gamma_m, const float* __restrict__ beta_m,
    const float* __restrict__ W1, const float* __restrict__ W3,
    __hip_bfloat16* __restrict__ v_bf, __hip_bfloat16* __restrict__ g_bf)
{
    const int row = blockIdx.x;        // s*384 + n
    const int tid = threadIdx.x;       // 0..255
    __shared__ float mhat[64];
    if (tid < 64) {
        float x = m_si[row * 64 + tid];
        float s1 = x, s2 = x * x;
        #pragma unroll
        for (int off = 32; off > 0; off >>= 1) {
            s1 += __shfl_xor(s1, off, 64);
            s2 += __shfl_xor(s2, off, 64);
        }
        float mu  = s1 * (1.0f / 64.0f);
        float var = s2 * (1.0f / 64.0f) - mu * mu;
        float rs  = rsqrtf(var + 1e-5f);
        mhat[tid] = (x - mu) * rs * gamma_m[tid] + beta_m[tid];
    }
    __syncthreads();
    float a1 = 0.f, a3 = 0.f;
    #pragma unroll 8
    for (int k = 0; k < 64; k++) {
        float mh = mhat[k];
        a1 = fmaf(mh, W1[k * 256 + tid], a1);
        a3 = fmaf(mh, W3[k * 256 + tid], a3);
    }
    v_bf[row * 256 + tid] = __float2bfloat16(a1);
    float g = 1.0f / (1.0f + __expf(-a3));
    g_bf[row * 256 + tid] = __float2bfloat16(g);
}

__global__ __launch_bounds__(128) void k2_ln_z(
    const float* __restrict__ z,
    const float* __restrict__ gamma_z, const float* __restrict__ beta_z,
    const float* __restrict__ W2, float* __restrict__ b_buf)
{
    const int row = blockIdx.x;        // i*384 + j
    const int tid = threadIdx.x;       // 0..127
    __shared__ float mhat[128];
    __shared__ float red[4];
    __shared__ float part[128];
    float x = z[row * 128 + tid];
    float s1 = x, s2 = x * x;
    #pragma unroll
    for (int off = 32; off > 0; off >>= 1) {
        s1 += __shfl_xor(s1, off, 64);
        s2 += __shfl_xor(s2, off, 64);
    }
    int wid = tid >> 6;
    if ((tid & 63) == 0) { red[wid * 2] = s1; red[wid * 2 + 1] = s2; }
    __syncthreads();
    s1 = red[0] + red[2];
    s2 = red[1] + red[3];
    float mu  = s1 * (1.0f / 128.0f);
    float var = s2 * (1.0f / 128.0f) - mu * mu;
    float rs  = rsqrtf(var + 1e-5f);
    mhat[tid] = (x - mu) * rs * gamma_z[tid] + beta_z[tid];
    __syncthreads();
    // partial dot products: tid = h*16 + ch, ch covers 8 k's each
    int h = tid >> 4, ch = tid & 15;
    float p = 0.f;
    #pragma unroll
    for (int kk = 0; kk < 8; kk++) {
        int k = ch * 8 + kk;
        p = fmaf(mhat[k], W2[k * 8 + h], p);
    }
    part[tid] = p;
    __syncthreads();
    if (tid < 8) {
        float acc = 0.f;
        #pragma unroll
        for (int c2 = 0; c2 < 16; c2++) acc += part[tid * 16 + c2];
        // layout [h][i][j], row = i*384+j
        b_buf[tid * 147456 + row] = acc;
    }
}

__global__ __launch_bounds__(128) void k3_softmax(float* __restrict__ w_buf)
{
    const int bx = blockIdx.x;         // h*384 + j
    const int h = bx / 384, j = bx % 384;
    const int tid = threadIdx.x;       // 0..127, covers i = tid, tid+128, tid+256
    float* base = w_buf + h * 147456 + j;
    float x0 = base[(tid      ) * 384];
    float x1 = base[(tid + 128) * 384];
    float x2 = base[(tid + 256) * 384];
    float m = fmaxf(x0, fmaxf(x1, x2));
    #pragma unroll
    for (int off = 32; off > 0; off >>= 1) m = fmaxf(m, __shfl_xor(m, off, 64));
    __shared__ float redm[2];
    __shared__ float reds[2];
    if ((tid & 63) == 0) redm[tid >> 6] = m;
    __syncthreads();
    m = fmaxf(redm[0], redm[1]);
    float e0 = __expf(x0 - m), e1 = __expf(x1 - m), e2 = __expf(x2 - m);
    float s = e0 + e1 + e2;
    #pragma unroll
    for (int off = 32; off > 0; off >>= 1) s += __shfl_xor(s, off, 64);
    if ((tid & 63) == 0) reds[tid >> 6] = s;
    __syncthreads();
    s = reds[0] + reds[1];
    float inv = 1.0f / s;
    base[(tid      ) * 384] = e0 * inv;
    base[(tid + 128) * 384] = e1 * inv;
    base[(tid + 256) * 384] = e2 * inv;
}

__global__ __launch_bounds__(256) void k4_einsum(
    const float* __restrict__ w_buf, const __hip_bfloat16* __restrict__ v_bf,
    const __hip_bfloat16* __restrict__ g_bf, const float* __restrict__ W4,
    float* __restrict__ out)
{
    const int bx = blockIdx.x;         // s*96 + it
    const int s  = bx / 96;
    const int i0 = (bx % 96) * 4;
    const int tid = threadIdx.x;       // h*32 + c
    const int h = tid >> 5;

    float acc0 = 0.f, acc1 = 0.f, acc2 = 0.f, acc3 = 0.f;
    const float* wp = w_buf + h * 147456 + i0 * 384;
    const __hip_bfloat16* vp = v_bf + s * 384 * 256 + tid;
    for (int j = 0; j < 384; j++) {
        float vv = __bfloat162float(vp[j * 256]);
        acc0 = fmaf(wp[j       ], vv, acc0);
        acc1 = fmaf(wp[j +  384], vv, acc1);
        acc2 = fmaf(wp[j +  768], vv, acc2);
        acc3 = fmaf(wp[j + 1152], vv, acc3);
    }

    __shared__ float o_l[4][256];
    const __hip_bfloat16* gp = g_bf + (s * 384 + i0) * 256 + tid;
    o_l[0][tid] = acc0 * __bfloat162float(gp[0]);
    o_l[1][tid] = acc1 * __bfloat162float(gp[256]);
    o_l[2][tid] = acc2 * __bfloat162float(gp[512]);
    o_l[3][tid] = acc3 * __bfloat162float(gp[768]);
    __syncthreads();

    const int ii = tid >> 6, d = tid & 63;
    float acc = 0.f;
    #pragma unroll 8
    for (int k = 0; k < 256; k++) {
        acc = fmaf(o_l[ii][k], W4[k * 64 + d], acc);
    }
    out[(s * 384 + i0 + ii) * 64 + d] = acc;
}

extern "C" void kernel_launch(void* const* d_in, const int* in_sizes, int n_in,
                              void* d_out, int out_size, void* d_ws, size_t ws_size,
                              hipStream_t stream)
{
    const float* m_si    = (const float*)d_in[0];
    const float* z_ij    = (const float*)d_in[1];
    const float* gamma_m = (const float*)d_in[2];
    const float* beta_m  = (const float*)d_in[3];
    const float* W1      = (const float*)d_in[4];
    const float* gamma_z = (const float*)d_in[5];
    const float* beta_z  = (const float*)d_in[6];
    const float* W2      = (const float*)d_in[7];
    const float* W3      = (const float*)d_in[8];
    const float* W4      = (const float*)d_in[9];
    float* out = (float*)d_out;

    // Workspace layout (needs ~206 MB):
    //   v_bf : 512*384*256 bf16 = 100663296 B
    //   g_bf : same            = 100663296 B
    //   w_buf: 8*384*384 fp32  =   4718592 B
    char* ws = (char*)d_ws;
    __hip_bfloat16* v_bf = (__hip_bfloat16*)ws;
    __hip_bfloat16* g_bf = (__hip_bfloat16*)(ws + 100663296);
    float* w_buf = (float*)(ws + 201326592);

    k1_ln_mv<<<196608, 256, 0, stream>>>(m_si, gamma_m, beta_m, W1, W3, v_bf, g_bf);
    k2_ln_z<<<147456, 128, 0, stream>>>(z_ij, gamma_z, beta_z, W2, w_buf);
    k3_softmax<<<3072, 128, 0, stream>>>(w_buf);
    k4_einsum<<<49152, 256, 0, stream>>>(w_buf, v_bf, g_bf, W4, out);
}

// Round 2
// 892.864 us; speedup vs baseline: 4.6108x; 4.6108x over previous
//
#include <hip/hip_runtime.h>
#include <hip/hip_bf16.h>
#include <math.h>

// Shapes: B=1, S=512, N=384, c_m=64, c_z=128, H=8, c=32  (HC = 256)
//
// Pipeline:
//  k0_w4t : W4[256,64] fp32 -> W4t[64][256] bf16 (for MFMA B-frags)
//  k1     : m = LN(m_si); v = m@W1 -> v_tg[s][h][c][j] bf16 (transposed!);
//           g = sigmoid(m@W3) -> g_bf[s][j][hc] bf16.  16 rows/block.
//  k2     : b = LN(z)@W2 -> w_buf[h][i][j] fp32
//  k3     : softmax over i (axis of stride 384) -> w_bf[h][i][j] bf16
//  k4     : MFMA: per (s, 64-i-tile): for h: O[64,32] = W_h[64,384]@V_sh[384,32],
//           gate, collect o_l[64][256] bf16 in LDS, then out = o_l @ W4 (MFMA).

typedef __attribute__((ext_vector_type(8))) short bf16x8;   // 8 bf16 = 4 VGPRs
typedef __attribute__((ext_vector_type(4))) float f32x4;

__global__ __launch_bounds__(256) void k0_w4t(
    const float* __restrict__ W4, __hip_bfloat16* __restrict__ W4t)
{
    int idx = blockIdx.x * 256 + threadIdx.x;   // 64*256 = 16384
    int d = idx >> 8, k = idx & 255;
    W4t[idx] = __float2bfloat16(W4[k * 64 + d]);
}

// ---------------------------------------------------------------------------
// k1: 16 rows (j's) of one s per block. grid = 512*24 = 12288, block 256.
__global__ __launch_bounds__(256) void k1_ln_mv(
    const float* __restrict__ m_si,
    const float* __restrict__ gamma_m, const float* __restrict__ beta_m,
    const float* __restrict__ W1, const float* __restrict__ W3,
    __hip_bfloat16* __restrict__ v_tg,   // [512][8][32][384]
    __hip_bfloat16* __restrict__ g_bf)   // [512][384][256]
{
    const int bx = blockIdx.x;
    const int s = bx / 24, j0 = (bx % 24) * 16;
    const int tid = threadIdx.x;
    const int lane = tid & 63, wv = tid >> 6;
    __shared__ float mhat[16][64];

    // phase 1: LN of rows j0..j0+15 (wave wv does rows 4wv..4wv+3)
    const float* mrow = m_si + (size_t)(s * 384 + j0) * 64;
    #pragma unroll
    for (int rr = 0; rr < 4; rr++) {
        int r = wv * 4 + rr;
        float x = mrow[r * 64 + lane];
        float s1 = x, s2 = x * x;
        #pragma unroll
        for (int off = 32; off > 0; off >>= 1) {
            s1 += __shfl_xor(s1, off, 64);
            s2 += __shfl_xor(s2, off, 64);
        }
        float mu  = s1 * (1.0f / 64.0f);
        float var = s2 * (1.0f / 64.0f) - mu * mu;
        float rs  = rsqrtf(var + 1e-5f);
        mhat[r][lane] = (x - mu) * rs * gamma_m[lane] + beta_m[lane];
    }
    __syncthreads();

    // phase 2: thread owns output column co for all 16 rows
    const int co = tid;
    float a1[16], a3[16];
    #pragma unroll
    for (int r = 0; r < 16; r++) { a1[r] = 0.f; a3[r] = 0.f; }
    for (int k = 0; k < 64; k += 4) {
        float w1a = W1[(k    ) * 256 + co], w3a = W3[(k    ) * 256 + co];
        float w1b = W1[(k + 1) * 256 + co], w3b = W3[(k + 1) * 256 + co];
        float w1c = W1[(k + 2) * 256 + co], w3c = W3[(k + 2) * 256 + co];
        float w1d = W1[(k + 3) * 256 + co], w3d = W3[(k + 3) * 256 + co];
        #pragma unroll
        for (int r = 0; r < 16; r++) {
            float4 m4 = *(const float4*)&mhat[r][k];   // broadcast b128
            a1[r] = fmaf(m4.x, w1a, a1[r]); a1[r] = fmaf(m4.y, w1b, a1[r]);
            a1[r] = fmaf(m4.z, w1c, a1[r]); a1[r] = fmaf(m4.w, w1d, a1[r]);
            a3[r] = fmaf(m4.x, w3a, a3[r]); a3[r] = fmaf(m4.y, w3b, a3[r]);
            a3[r] = fmaf(m4.z, w3c, a3[r]); a3[r] = fmaf(m4.w, w3d, a3[r]);
        }
    }

    // phase 3a: g (coalesced, [s][j][hc])
    #pragma unroll
    for (int r = 0; r < 16; r++) {
        float g = 1.0f / (1.0f + __expf(-a3[r]));
        g_bf[(size_t)(s * 384 + j0 + r) * 256 + co] = __float2bfloat16(g);
    }
    // phase 3b: v transposed ([s][h][c][j]); thread owns hc=co, 16 consecutive j
    bf16x8 lo, hi;
    #pragma unroll
    for (int r = 0; r < 8; r++) {
        __hip_bfloat16 b0 = __float2bfloat16(a1[r]);
        __hip_bfloat16 b1 = __float2bfloat16(a1[r + 8]);
        lo[r] = *(short*)&b0;
        hi[r] = *(short*)&b1;
    }
    short* vp = (short*)v_tg + (size_t)s * 98304 + co * 384 + j0;
    *(bf16x8*)vp = lo;
    *(bf16x8*)(vp + 8) = hi;
}

// ---------------------------------------------------------------------------
__global__ __launch_bounds__(128) void k2_ln_z(
    const float* __restrict__ z,
    const float* __restrict__ gamma_z, const float* __restrict__ beta_z,
    const float* __restrict__ W2, float* __restrict__ b_buf)
{
    const int row = blockIdx.x;        // i*384 + j
    const int tid = threadIdx.x;       // 0..127
    __shared__ float mhat[128];
    __shared__ float red[4];
    __shared__ float part[128];
    float x = z[(size_t)row * 128 + tid];
    float s1 = x, s2 = x * x;
    #pragma unroll
    for (int off = 32; off > 0; off >>= 1) {
        s1 += __shfl_xor(s1, off, 64);
        s2 += __shfl_xor(s2, off, 64);
    }
    int wid = tid >> 6;
    if ((tid & 63) == 0) { red[wid * 2] = s1; red[wid * 2 + 1] = s2; }
    __syncthreads();
    s1 = red[0] + red[2];
    s2 = red[1] + red[3];
    float mu  = s1 * (1.0f / 128.0f);
    float var = s2 * (1.0f / 128.0f) - mu * mu;
    float rs  = rsqrtf(var + 1e-5f);
    mhat[tid] = (x - mu) * rs * gamma_z[tid] + beta_z[tid];
    __syncthreads();
    int h = tid >> 4, ch = tid & 15;
    float p = 0.f;
    #pragma unroll
    for (int kk = 0; kk < 8; kk++) {
        int k = ch * 8 + kk;
        p = fmaf(mhat[k], W2[k * 8 + h], p);
    }
    part[tid] = p;
    __syncthreads();
    if (tid < 8) {
        float acc = 0.f;
        #pragma unroll
        for (int c2 = 0; c2 < 16; c2++) acc += part[tid * 16 + c2];
        b_buf[(size_t)tid * 147456 + row] = acc;   // [h][i][j]
    }
}

// ---------------------------------------------------------------------------
__global__ __launch_bounds__(128) void k3_softmax(
    const float* __restrict__ w_buf, __hip_bfloat16* __restrict__ w_bf)
{
    const int bx = blockIdx.x;         // h*384 + j
    const int h = bx / 384, j = bx % 384;
    const int tid = threadIdx.x;       // i = tid, tid+128, tid+256
    const float* base = w_buf + (size_t)h * 147456 + j;
    float x0 = base[(tid      ) * 384];
    float x1 = base[(tid + 128) * 384];
    float x2 = base[(tid + 256) * 384];
    float m = fmaxf(x0, fmaxf(x1, x2));
    #pragma unroll
    for (int off = 32; off > 0; off >>= 1) m = fmaxf(m, __shfl_xor(m, off, 64));
    __shared__ float redm[2];
    __shared__ float reds[2];
    if ((tid & 63) == 0) redm[tid >> 6] = m;
    __syncthreads();
    m = fmaxf(redm[0], redm[1]);
    float e0 = __expf(x0 - m), e1 = __expf(x1 - m), e2 = __expf(x2 - m);
    float s = e0 + e1 + e2;
    #pragma unroll
    for (int off = 32; off > 0; off >>= 1) s += __shfl_xor(s, off, 64);
    if ((tid & 63) == 0) reds[tid >> 6] = s;
    __syncthreads();
    s = reds[0] + reds[1];
    float inv = 1.0f / s;
    __hip_bfloat16* ob = w_bf + (size_t)h * 147456 + j;
    ob[(tid      ) * 384] = __float2bfloat16(e0 * inv);
    ob[(tid + 128) * 384] = __float2bfloat16(e1 * inv);
    ob[(tid + 256) * 384] = __float2bfloat16(e2 * inv);
}

// ---------------------------------------------------------------------------
// k4: MFMA einsum + gate + @W4.  grid = 512*6 = 3072 blocks, 256 threads.
#define VSTR 392   // LDS v_t stride: 784 B -> b128 superbank step = 49 % 8 = 1
#define OSTR 264   // LDS o_l stride: 528 B -> superbank step = 33 % 8 = 1

__global__ __launch_bounds__(256) void k4_mfma(
    const __hip_bfloat16* __restrict__ w_bf,   // [8][384][384]
    const __hip_bfloat16* __restrict__ v_tg,   // [512][8][32][384]
    const __hip_bfloat16* __restrict__ g_bf,   // [512][384][256]
    const __hip_bfloat16* __restrict__ W4t,    // [64][256]
    float* __restrict__ out)                   // [512][384][64]
{
    __shared__ short v_t[32 * VSTR];           // 25088 B
    __shared__ short o_l[64 * OSTR];           // 33792 B
    const int bx = blockIdx.x;
    const int s = bx / 6, i0 = (bx % 6) * 64;
    const int tid = threadIdx.x;
    const int lane = tid & 63, wv = tid >> 6;
    const int col = lane & 15, quad = lane >> 4;

    // A-frag base: lane holds w[h][i0+wv*16+col][k0 + quad*8 + 0..7]
    const short* wA_base = (const short*)w_bf
        + (size_t)(i0 + wv * 16 + col) * 384 + quad * 8;
    const short* vslab = (const short*)v_tg + (size_t)s * 98304;
    const __hip_bfloat16* gbase = g_bf + (size_t)(s * 384 + i0) * 256;

    #pragma unroll 1
    for (int h = 0; h < 8; h++) {
        __syncthreads();                       // prior-h v_t reads done
        // stage v_tg[s][h][*][*] (24 KB) into padded LDS: 1536 chunks of 16B
        {
            const short* src = vslab + h * 12288;
            #pragma unroll
            for (int r = 0; r < 6; r++) {
                int chunk = r * 256 + tid;
                int cc = chunk / 48, j8 = chunk % 48;
                *(bf16x8*)&v_t[cc * VSTR + j8 * 8] =
                    *(const bf16x8*)(src + cc * 384 + j8 * 8);
            }
        }
        __syncthreads();

        f32x4 acc0 = {0.f, 0.f, 0.f, 0.f}, acc1 = {0.f, 0.f, 0.f, 0.f};
        const short* wA = wA_base + (size_t)h * 147456;
        #pragma unroll
        for (int ks = 0; ks < 12; ks++) {
            int k0 = ks * 32;
            bf16x8 a  = *(const bf16x8*)(wA + k0);
            bf16x8 b0 = *(const bf16x8*)&v_t[(     col) * VSTR + k0 + quad * 8];
            bf16x8 b1 = *(const bf16x8*)&v_t[(16 + col) * VSTR + k0 + quad * 8];
            acc0 = __builtin_amdgcn_mfma_f32_16x16x32_bf16(a, b0, acc0, 0, 0, 0);
            acc1 = __builtin_amdgcn_mfma_f32_16x16x32_bf16(a, b1, acc1, 0, 0, 0);
        }
        // epilogue: gate + park in o_l (bf16).  D: row = quad*4+reg, col = lane&15
        int ibase = wv * 16 + quad * 4;
        #pragma unroll
        for (int reg = 0; reg < 4; reg++) {
            int il = ibase + reg;
            float g0 = __bfloat162float(gbase[il * 256 + h * 32 + col]);
            float g1 = __bfloat162float(gbase[il * 256 + h * 32 + 16 + col]);
            __hip_bfloat16 t0 = __float2bfloat16(acc0[reg] * g0);
            __hip_bfloat16 t1 = __float2bfloat16(acc1[reg] * g1);
            o_l[il * OSTR + h * 32 + col]      = *(short*)&t0;
            o_l[il * OSTR + h * 32 + 16 + col] = *(short*)&t1;
        }
    }

    // GEMM2: out[16i x 64d] per wave = o_l[16 x 256] @ W4.  Each wave reads only
    // rows it wrote (wv*16 + 0..15) -> no barrier needed (same-wave LDS order).
    f32x4 acc2[4];
    #pragma unroll
    for (int n = 0; n < 4; n++) acc2[n] = (f32x4){0.f, 0.f, 0.f, 0.f};
    #pragma unroll
    for (int ks = 0; ks < 8; ks++) {
        int k0 = ks * 32;
        bf16x8 a = *(const bf16x8*)&o_l[(wv * 16 + col) * OSTR + k0 + quad * 8];
        #pragma unroll
        for (int n = 0; n < 4; n++) {
            bf16x8 b = *(const bf16x8*)((const short*)W4t
                        + (n * 16 + col) * 256 + k0 + quad * 8);
            acc2[n] = __builtin_amdgcn_mfma_f32_16x16x32_bf16(a, b, acc2[n], 0, 0, 0);
        }
    }
    float* obase = out + (size_t)(s * 384 + i0 + wv * 16 + quad * 4) * 64;
    #pragma unroll
    for (int n = 0; n < 4; n++)
        #pragma unroll
        for (int reg = 0; reg < 4; reg++)
            obase[reg * 64 + n * 16 + col] = acc2[n][reg];
}

// ---------------------------------------------------------------------------
extern "C" void kernel_launch(void* const* d_in, const int* in_sizes, int n_in,
                              void* d_out, int out_size, void* d_ws, size_t ws_size,
                              hipStream_t stream)
{
    const float* m_si    = (const float*)d_in[0];
    const float* z_ij    = (const float*)d_in[1];
    const float* gamma_m = (const float*)d_in[2];
    const float* beta_m  = (const float*)d_in[3];
    const float* W1      = (const float*)d_in[4];
    const float* gamma_z = (const float*)d_in[5];
    const float* beta_z  = (const float*)d_in[6];
    const float* W2      = (const float*)d_in[7];
    const float* W3      = (const float*)d_in[8];
    const float* W4      = (const float*)d_in[9];
    float* out = (float*)d_out;

    // ws layout (208.4 MB total):
    //   g_bf : 100663296 B   v_tg : 100663296 B   w_buf(fp32): 4718592 B
    //   w_bf : 2359296 B     W4t  : 32768 B
    char* ws = (char*)d_ws;
    __hip_bfloat16* g_bf = (__hip_bfloat16*)ws;
    __hip_bfloat16* v_tg = (__hip_bfloat16*)(ws + 100663296);
    float*          w_buf = (float*)(ws + 201326592);
    __hip_bfloat16* w_bf = (__hip_bfloat16*)(ws + 206045184);
    __hip_bfloat16* W4t  = (__hip_bfloat16*)(ws + 208404480);

    k0_w4t  <<<64,     256, 0, stream>>>(W4, W4t);
    k1_ln_mv<<<12288,  256, 0, stream>>>(m_si, gamma_m, beta_m, W1, W3, v_tg, g_bf);
    k2_ln_z <<<147456, 128, 0, stream>>>(z_ij, gamma_z, beta_z, W2, w_buf);
    k3_softmax<<<3072, 128, 0, stream>>>(w_buf, w_bf);
    k4_mfma <<<3072,   256, 0, stream>>>(w_bf, v_tg, g_bf, W4t, out);
}

// Round 3
// 642.425 us; speedup vs baseline: 6.4083x; 1.3898x over previous
//
#include <hip/hip_runtime.h>
#include <hip/hip_bf16.h>
#include <math.h>

// Shapes: B=1, S=512, N=384, c_m=64, c_z=128, H=8, c=32  (HC = 256)
//
// Pipeline:
//  k0_w4t : W4[256,64] fp32 -> W4t[64][256] bf16 (for MFMA B-frags)
//  k1     : m = LN(m_si); v = m@W1 -> v_tg[s][h][c][j] bf16 (transposed!);
//           g = sigmoid(m@W3) -> g_bf[s][j][hc] bf16.  16 rows/block.
//  k2     : b = LN(z)@W2 -> w_buf[h][i][j] fp32   (64 rows/block, fold-reduce)
//  k3a    : partial online softmax (m,l) per (h, 16-i-chunk, j)
//  k3m    : combine 24 partials -> M[h][j], invL[h][j]
//  k3b    : w_bf[h][i][j] = bf16( exp(x - M) * invL )
//  k4     : MFMA: per (s, 64-i-tile): for h: O[64,32] = W_h[64,384]@V_sh[384,32],
//           gate, collect o_l[64][256] bf16 in LDS, then out = o_l @ W4 (MFMA).

typedef __attribute__((ext_vector_type(8))) short bf16x8;   // 8 bf16 = 4 VGPRs
typedef __attribute__((ext_vector_type(4))) float f32x4;

__global__ __launch_bounds__(256) void k0_w4t(
    const float* __restrict__ W4, __hip_bfloat16* __restrict__ W4t)
{
    int idx = blockIdx.x * 256 + threadIdx.x;   // 64*256 = 16384
    int d = idx >> 8, k = idx & 255;
    W4t[idx] = __float2bfloat16(W4[k * 64 + d]);
}

// ---------------------------------------------------------------------------
// k1: 16 rows (j's) of one s per block. grid = 512*24 = 12288, block 256.
__global__ __launch_bounds__(256) void k1_ln_mv(
    const float* __restrict__ m_si,
    const float* __restrict__ gamma_m, const float* __restrict__ beta_m,
    const float* __restrict__ W1, const float* __restrict__ W3,
    __hip_bfloat16* __restrict__ v_tg,   // [512][8][32][384]
    __hip_bfloat16* __restrict__ g_bf)   // [512][384][256]
{
    const int bx = blockIdx.x;
    const int s = bx / 24, j0 = (bx % 24) * 16;
    const int tid = threadIdx.x;
    const int lane = tid & 63, wv = tid >> 6;
    __shared__ float mhat[16][64];

    const float* mrow = m_si + (size_t)(s * 384 + j0) * 64;
    #pragma unroll
    for (int rr = 0; rr < 4; rr++) {
        int r = wv * 4 + rr;
        float x = mrow[r * 64 + lane];
        float s1 = x, s2 = x * x;
        #pragma unroll
        for (int off = 32; off > 0; off >>= 1) {
            s1 += __shfl_xor(s1, off, 64);
            s2 += __shfl_xor(s2, off, 64);
        }
        float mu  = s1 * (1.0f / 64.0f);
        float var = s2 * (1.0f / 64.0f) - mu * mu;
        float rs  = rsqrtf(var + 1e-5f);
        mhat[r][lane] = (x - mu) * rs * gamma_m[lane] + beta_m[lane];
    }
    __syncthreads();

    const int co = tid;
    float a1[16], a3[16];
    #pragma unroll
    for (int r = 0; r < 16; r++) { a1[r] = 0.f; a3[r] = 0.f; }
    for (int k = 0; k < 64; k += 4) {
        float w1a = W1[(k    ) * 256 + co], w3a = W3[(k    ) * 256 + co];
        float w1b = W1[(k + 1) * 256 + co], w3b = W3[(k + 1) * 256 + co];
        float w1c = W1[(k + 2) * 256 + co], w3c = W3[(k + 2) * 256 + co];
        float w1d = W1[(k + 3) * 256 + co], w3d = W3[(k + 3) * 256 + co];
        #pragma unroll
        for (int r = 0; r < 16; r++) {
            float4 m4 = *(const float4*)&mhat[r][k];   // broadcast b128
            a1[r] = fmaf(m4.x, w1a, a1[r]); a1[r] = fmaf(m4.y, w1b, a1[r]);
            a1[r] = fmaf(m4.z, w1c, a1[r]); a1[r] = fmaf(m4.w, w1d, a1[r]);
            a3[r] = fmaf(m4.x, w3a, a3[r]); a3[r] = fmaf(m4.y, w3b, a3[r]);
            a3[r] = fmaf(m4.z, w3c, a3[r]); a3[r] = fmaf(m4.w, w3d, a3[r]);
        }
    }

    #pragma unroll
    for (int r = 0; r < 16; r++) {
        float g = 1.0f / (1.0f + __expf(-a3[r]));
        g_bf[(size_t)(s * 384 + j0 + r) * 256 + co] = __float2bfloat16(g);
    }
    bf16x8 lo, hi;
    #pragma unroll
    for (int r = 0; r < 8; r++) {
        __hip_bfloat16 b0 = __float2bfloat16(a1[r]);
        __hip_bfloat16 b1 = __float2bfloat16(a1[r + 8]);
        lo[r] = *(short*)&b0;
        hi[r] = *(short*)&b1;
    }
    short* vp = (short*)v_tg + (size_t)s * 98304 + co * 384 + j0;
    *(bf16x8*)vp = lo;
    *(bf16x8*)(vp + 8) = hi;
}

// ---------------------------------------------------------------------------
// k2: 64 rows/block, 4 waves, one wave per row step. grid = 2304.
__global__ __launch_bounds__(256) void k2_ln_z(
    const float* __restrict__ z,
    const float* __restrict__ gamma_z, const float* __restrict__ beta_z,
    const float* __restrict__ W2, float* __restrict__ b_buf)
{
    const int tid = threadIdx.x;
    const int lane = tid & 63, wv = tid >> 6;
    const int R0 = blockIdx.x * 64;
    __shared__ float part[64][9];       // [row_local][h], stride 9 = conflict-free

    // per-lane constants: k-pair 2*lane, 2*lane+1
    float2 g2 = *(const float2*)&gamma_z[lane * 2];
    float2 be2 = *(const float2*)&beta_z[lane * 2];
    float4 w2a = *(const float4*)&W2[lane * 16];       // W2[2*lane][0..3]
    float4 w2b = *(const float4*)&W2[lane * 16 + 4];   // W2[2*lane][4..7]
    float4 w2c = *(const float4*)&W2[lane * 16 + 8];   // W2[2*lane+1][0..3]
    float4 w2d = *(const float4*)&W2[lane * 16 + 12];  // W2[2*lane+1][4..7]

    const bool hi4 = (lane & 4) != 0;
    const bool hi2 = (lane & 2) != 0;
    const bool hi1 = (lane & 1) != 0;

    float2 zx = *(const float2*)&z[(size_t)(R0 + wv * 16) * 128 + lane * 2];
    #pragma unroll 1
    for (int rr = 0; rr < 16; rr++) {
        const int rl = wv * 16 + rr;
        float x0 = zx.x, x1 = zx.y;
        if (rr < 15)
            zx = *(const float2*)&z[(size_t)(R0 + rl + 1) * 128 + lane * 2];

        float s1 = x0 + x1, s2 = x0 * x0 + x1 * x1;
        #pragma unroll
        for (int off = 32; off > 0; off >>= 1) {
            s1 += __shfl_xor(s1, off, 64);
            s2 += __shfl_xor(s2, off, 64);
        }
        float mu  = s1 * (1.0f / 128.0f);
        float var = s2 * (1.0f / 128.0f) - mu * mu;
        float rs  = rsqrtf(var + 1e-5f);
        float mh0 = (x0 - mu) * rs * g2.x + be2.x;
        float mh1 = (x1 - mu) * rs * g2.y + be2.y;

        float p[8];
        p[0] = fmaf(mh0, w2a.x, mh1 * w2c.x);
        p[1] = fmaf(mh0, w2a.y, mh1 * w2c.y);
        p[2] = fmaf(mh0, w2a.z, mh1 * w2c.z);
        p[3] = fmaf(mh0, w2a.w, mh1 * w2c.w);
        p[4] = fmaf(mh0, w2b.x, mh1 * w2d.x);
        p[5] = fmaf(mh0, w2b.y, mh1 * w2d.y);
        p[6] = fmaf(mh0, w2b.z, mh1 * w2d.z);
        p[7] = fmaf(mh0, w2b.w, mh1 * w2d.w);

        // fold: value-split on lane bits 2,1,0 -> h = lane&7
        float t[4];
        #pragma unroll
        for (int k = 0; k < 4; k++) {
            float keep = hi4 ? p[k + 4] : p[k];
            float send = hi4 ? p[k] : p[k + 4];
            t[k] = keep + __shfl_xor(send, 4, 64);
        }
        float u[2];
        #pragma unroll
        for (int k = 0; k < 2; k++) {
            float keep = hi2 ? t[k + 2] : t[k];
            float send = hi2 ? t[k] : t[k + 2];
            u[k] = keep + __shfl_xor(send, 2, 64);
        }
        float vsum;
        {
            float keep = hi1 ? u[1] : u[0];
            float send = hi1 ? u[0] : u[1];
            vsum = keep + __shfl_xor(send, 1, 64);
        }
        vsum += __shfl_xor(vsum, 8, 64);
        vsum += __shfl_xor(vsum, 16, 64);
        vsum += __shfl_xor(vsum, 32, 64);
        if (lane < 8) part[rl][lane] = vsum;   // h = lane
    }
    __syncthreads();

    // write: 512 outputs, thread t writes (h=t>>6, rl=t&63) and (h+4, rl)
    {
        int h0 = tid >> 6, rl = tid & 63;
        b_buf[(size_t)h0 * 147456 + R0 + rl]       = part[rl][h0];
        b_buf[(size_t)(h0 + 4) * 147456 + R0 + rl] = part[rl][h0 + 4];
    }
}

// ---------------------------------------------------------------------------
// k3a: partial online softmax over 16-i chunks. grid = 8*24 = 192, block 128.
__global__ __launch_bounds__(128) void k3a_part(
    const float* __restrict__ w_buf, float* __restrict__ pm, float* __restrict__ pl)
{
    const int h = blockIdx.x / 24, ic = blockIdx.x % 24;
    const int i0 = ic * 16;
    const int tid = threadIdx.x;
    const float* base = w_buf + ((size_t)h * 384 + i0) * 384;

    float m0 = -INFINITY, m1 = -INFINITY, m2 = -INFINITY;
    float l0 = 0.f, l1 = 0.f, l2 = 0.f;
    #pragma unroll 4
    for (int ii = 0; ii < 16; ii++) {
        float x0 = base[ii * 384 + tid];
        float x1 = base[ii * 384 + tid + 128];
        float x2 = base[ii * 384 + tid + 256];
        float n0 = fmaxf(m0, x0);
        l0 = l0 * __expf(m0 - n0) + __expf(x0 - n0); m0 = n0;
        float n1 = fmaxf(m1, x1);
        l1 = l1 * __expf(m1 - n1) + __expf(x1 - n1); m1 = n1;
        float n2 = fmaxf(m2, x2);
        l2 = l2 * __expf(m2 - n2) + __expf(x2 - n2); m2 = n2;
    }
    float* pmb = pm + ((size_t)h * 24 + ic) * 384;
    float* plb = pl + ((size_t)h * 24 + ic) * 384;
    pmb[tid]       = m0;  plb[tid]       = l0;
    pmb[tid + 128] = m1;  plb[tid + 128] = l1;
    pmb[tid + 256] = m2;  plb[tid + 256] = l2;
}

// k3m: combine 24 partials -> M, invL. grid = 8 blocks, 384 threads.
__global__ __launch_bounds__(384) void k3m_comb(
    const float* __restrict__ pm, const float* __restrict__ pl,
    float* __restrict__ Mf, float* __restrict__ invLf)
{
    const int h = blockIdx.x, j = threadIdx.x;
    float M = -INFINITY, L = 0.f;
    #pragma unroll 4
    for (int ic = 0; ic < 24; ic++) {
        float m = pm[((size_t)h * 24 + ic) * 384 + j];
        float l = pl[((size_t)h * 24 + ic) * 384 + j];
        float nM = fmaxf(M, m);
        L = L * __expf(M - nM) + l * __expf(m - nM);
        M = nM;
    }
    Mf[h * 384 + j] = M;
    invLf[h * 384 + j] = 1.0f / L;
}

// k3b: write normalized bf16 weights. grid = 192, block 128.
__global__ __launch_bounds__(128) void k3b_write(
    const float* __restrict__ w_buf, const float* __restrict__ Mf,
    const float* __restrict__ invLf, __hip_bfloat16* __restrict__ w_bf)
{
    const int h = blockIdx.x / 24, ic = blockIdx.x % 24;
    const int i0 = ic * 16;
    const int tid = threadIdx.x;
    const float* base = w_buf + ((size_t)h * 384 + i0) * 384;
    __hip_bfloat16* ob = w_bf + ((size_t)h * 384 + i0) * 384;

    float M0 = Mf[h * 384 + tid],       iL0 = invLf[h * 384 + tid];
    float M1 = Mf[h * 384 + tid + 128], iL1 = invLf[h * 384 + tid + 128];
    float M2 = Mf[h * 384 + tid + 256], iL2 = invLf[h * 384 + tid + 256];
    #pragma unroll 4
    for (int ii = 0; ii < 16; ii++) {
        float x0 = base[ii * 384 + tid];
        float x1 = base[ii * 384 + tid + 128];
        float x2 = base[ii * 384 + tid + 256];
        ob[ii * 384 + tid]       = __float2bfloat16(__expf(x0 - M0) * iL0);
        ob[ii * 384 + tid + 128] = __float2bfloat16(__expf(x1 - M1) * iL1);
        ob[ii * 384 + tid + 256] = __float2bfloat16(__expf(x2 - M2) * iL2);
    }
}

// ---------------------------------------------------------------------------
// k4: MFMA einsum + gate + @W4.  grid = 512*6 = 3072 blocks, 256 threads.
#define VSTR 392   // LDS v_t stride: 784 B -> b128 superbank step = 49 % 8 = 1
#define OSTR 264   // LDS o_l stride: 528 B -> superbank step = 33 % 8 = 1

__global__ __launch_bounds__(256) void k4_mfma(
    const __hip_bfloat16* __restrict__ w_bf,   // [8][384][384]
    const __hip_bfloat16* __restrict__ v_tg,   // [512][8][32][384]
    const __hip_bfloat16* __restrict__ g_bf,   // [512][384][256]
    const __hip_bfloat16* __restrict__ W4t,    // [64][256]
    float* __restrict__ out)                   // [512][384][64]
{
    __shared__ short v_t[32 * VSTR];           // 25088 B
    __shared__ short o_l[64 * OSTR];           // 33792 B
    const int bx = blockIdx.x;
    const int s = bx / 6, i0 = (bx % 6) * 64;
    const int tid = threadIdx.x;
    const int lane = tid & 63, wv = tid >> 6;
    const int col = lane & 15, quad = lane >> 4;

    const short* wA_base = (const short*)w_bf
        + (size_t)(i0 + wv * 16 + col) * 384 + quad * 8;
    const short* vslab = (const short*)v_tg + (size_t)s * 98304;
    const __hip_bfloat16* gbase = g_bf + (size_t)(s * 384 + i0) * 256;

    #pragma unroll 1
    for (int h = 0; h < 8; h++) {
        __syncthreads();
        {
            const short* src = vslab + h * 12288;
            #pragma unroll
            for (int r = 0; r < 6; r++) {
                int chunk = r * 256 + tid;
                int cc = chunk / 48, j8 = chunk % 48;
                *(bf16x8*)&v_t[cc * VSTR + j8 * 8] =
                    *(const bf16x8*)(src + cc * 384 + j8 * 8);
            }
        }
        __syncthreads();

        f32x4 acc0 = {0.f, 0.f, 0.f, 0.f}, acc1 = {0.f, 0.f, 0.f, 0.f};
        const short* wA = wA_base + (size_t)h * 147456;
        #pragma unroll
        for (int ks = 0; ks < 12; ks++) {
            int k0 = ks * 32;
            bf16x8 a  = *(const bf16x8*)(wA + k0);
            bf16x8 b0 = *(const bf16x8*)&v_t[(     col) * VSTR + k0 + quad * 8];
            bf16x8 b1 = *(const bf16x8*)&v_t[(16 + col) * VSTR + k0 + quad * 8];
            acc0 = __builtin_amdgcn_mfma_f32_16x16x32_bf16(a, b0, acc0, 0, 0, 0);
            acc1 = __builtin_amdgcn_mfma_f32_16x16x32_bf16(a, b1, acc1, 0, 0, 0);
        }
        int ibase = wv * 16 + quad * 4;
        #pragma unroll
        for (int reg = 0; reg < 4; reg++) {
            int il = ibase + reg;
            float g0 = __bfloat162float(gbase[il * 256 + h * 32 + col]);
            float g1 = __bfloat162float(gbase[il * 256 + h * 32 + 16 + col]);
            __hip_bfloat16 t0 = __float2bfloat16(acc0[reg] * g0);
            __hip_bfloat16 t1 = __float2bfloat16(acc1[reg] * g1);
            o_l[il * OSTR + h * 32 + col]      = *(short*)&t0;
            o_l[il * OSTR + h * 32 + 16 + col] = *(short*)&t1;
        }
    }

    f32x4 acc2[4];
    #pragma unroll
    for (int n = 0; n < 4; n++) acc2[n] = (f32x4){0.f, 0.f, 0.f, 0.f};
    #pragma unroll
    for (int ks = 0; ks < 8; ks++) {
        int k0 = ks * 32;
        bf16x8 a = *(const bf16x8*)&o_l[(wv * 16 + col) * OSTR + k0 + quad * 8];
        #pragma unroll
        for (int n = 0; n < 4; n++) {
            bf16x8 b = *(const bf16x8*)((const short*)W4t
                        + (n * 16 + col) * 256 + k0 + quad * 8);
            acc2[n] = __builtin_amdgcn_mfma_f32_16x16x32_bf16(a, b, acc2[n], 0, 0, 0);
        }
    }
    float* obase = out + (size_t)(s * 384 + i0 + wv * 16 + quad * 4) * 64;
    #pragma unroll
    for (int n = 0; n < 4; n++)
        #pragma unroll
        for (int reg = 0; reg < 4; reg++)
            obase[reg * 64 + n * 16 + col] = acc2[n][reg];
}

// ---------------------------------------------------------------------------
extern "C" void kernel_launch(void* const* d_in, const int* in_sizes, int n_in,
                              void* d_out, int out_size, void* d_ws, size_t ws_size,
                              hipStream_t stream)
{
    const float* m_si    = (const float*)d_in[0];
    const float* z_ij    = (const float*)d_in[1];
    const float* gamma_m = (const float*)d_in[2];
    const float* beta_m  = (const float*)d_in[3];
    const float* W1      = (const float*)d_in[4];
    const float* gamma_z = (const float*)d_in[5];
    const float* beta_z  = (const float*)d_in[6];
    const float* W2      = (const float*)d_in[7];
    const float* W3      = (const float*)d_in[8];
    const float* W4      = (const float*)d_in[9];
    float* out = (float*)d_out;

    // ws layout (~209.0 MB):
    //   g_bf : 100663296 B   v_tg : 100663296 B   w_buf(fp32): 4718592 B
    //   w_bf : 2359296 B     W4t  : 32768 B
    //   pm/pl: 294912 B each   Mf/invLf: 12288 B each
    char* ws = (char*)d_ws;
    __hip_bfloat16* g_bf = (__hip_bfloat16*)ws;
    __hip_bfloat16* v_tg = (__hip_bfloat16*)(ws + 100663296);
    float*          w_buf = (float*)(ws + 201326592);
    __hip_bfloat16* w_bf = (__hip_bfloat16*)(ws + 206045184);
    __hip_bfloat16* W4t  = (__hip_bfloat16*)(ws + 208404480);
    float* pm    = (float*)(ws + 208437248);
    float* pl    = (float*)(ws + 208732160);
    float* Mf    = (float*)(ws + 209027072);
    float* invLf = (float*)(ws + 209039360);

    k0_w4t   <<<64,    256, 0, stream>>>(W4, W4t);
    k1_ln_mv <<<12288, 256, 0, stream>>>(m_si, gamma_m, beta_m, W1, W3, v_tg, g_bf);
    k2_ln_z  <<<2304,  256, 0, stream>>>(z_ij, gamma_z, beta_z, W2, w_buf);
    k3a_part <<<192,   128, 0, stream>>>(w_buf, pm, pl);
    k3m_comb <<<8,     384, 0, stream>>>(pm, pl, Mf, invLf);
    k3b_write<<<192,   128, 0, stream>>>(w_buf, Mf, invLf, w_bf);
    k4_mfma  <<<3072,  256, 0, stream>>>(w_bf, v_tg, g_bf, W4t, out);
}